// Round 2
// baseline (540.005 us; speedup 1.0000x reference)
//
#include <hip/hip_runtime.h>

#define H 32
#define FOUR_H 128
#define SEQ 512
#define BM 16          // batch rows per block
#define NTHREADS 512   // 8 waves
#define GSTRIDE 17     // padded stride for Gbuf [128 n][16 m]

typedef __attribute__((ext_vector_type(8))) short short8;
typedef __attribute__((ext_vector_type(4))) float f32x4;

__device__ __forceinline__ short f2bf(float f) {
    unsigned u = __float_as_uint(f);
    unsigned r = (u + 0x7FFFu + ((u >> 16) & 1u)) >> 16;
    return (short)r;
}
__device__ __forceinline__ float bf2f(short s) {
    return __uint_as_float(((unsigned)(unsigned short)s) << 16);
}
__device__ __forceinline__ float fast_sigmoid(float x) {
    float e = __expf(-x);
    return __builtin_amdgcn_rcpf(1.0f + e);
}
__device__ __forceinline__ float fast_tanh(float x) {
    float e = __expf(2.0f * x);
    return 1.0f - 2.0f * __builtin_amdgcn_rcpf(1.0f + e);
}

__global__ __launch_bounds__(NTHREADS, 2) void lstm_kernel(
    const float* __restrict__ x,      // [4096,512]
    const float* __restrict__ w_ih0,  // [128,1]
    const float* __restrict__ w_hh0,  // [128,32]
    const float* __restrict__ b_ih0, const float* __restrict__ b_hh0,
    const float* __restrict__ w_ih1,  // [128,32]
    const float* __restrict__ w_hh1,  // [128,32]
    const float* __restrict__ b_ih1, const float* __restrict__ b_hh1,
    const float* __restrict__ fc1_w,  // [16,32]
    const float* __restrict__ fc1_b,  // [16]
    const float* __restrict__ fc2_w,  // [1,16]
    const float* __restrict__ fc2_b,  // [1]
    float* __restrict__ out)          // [4096]
{
    __shared__ __align__(16) float xbuf[BM * SEQ];          // 32 KB
    __shared__ __align__(16) float Gbuf[FOUR_H * GSTRIDE];  // 8.7 KB
    __shared__ __align__(16) short h1hi[BM * H];
    __shared__ __align__(16) short h1lo[BM * H];
    __shared__ __align__(16) short h2hi[BM * H];
    __shared__ __align__(16) short h2lo[BM * H];
    __shared__ __align__(16) float h2f[BM * 33];
    __shared__ __align__(16) float yb[BM * 17];

    const int tid  = threadIdx.x;
    const int lane = tid & 63;
    const int wv   = tid >> 6;          // wave id 0..7 -> owns N-tile wv
    const int r0   = blockIdx.x * BM;

    // stage x slice [16 rows x 512 steps], fully coalesced
    for (int i = tid; i < BM * SEQ; i += NTHREADS)
        xbuf[i] = x[r0 * SEQ + i];

    // zero hidden state buffers (h0 = 0)
    for (int i = tid; i < BM * H; i += NTHREADS) {
        h1hi[i] = 0; h1lo[i] = 0; h2hi[i] = 0; h2lo[i] = 0;
    }

    // --- B fragments in registers, split-bf16 (w = whi + wlo) ---
    // B-frag for mfma_f32_16x16x32_bf16, W row-major [n][k]:
    //   n = wv*16 + (lane&15), k = (lane>>4)*8 + j
    const int fn = wv * 16 + (lane & 15);
    const int fk = (lane >> 4) * 8;
    short8 b1hi, b1lo, bihi, bilo, bhhi, bhlo;
    {
        const float* p = &w_hh0[fn * H + fk];
        #pragma unroll
        for (int j = 0; j < 8; ++j) { float v = p[j]; short h = f2bf(v); b1hi[j] = h; b1lo[j] = f2bf(v - bf2f(h)); }
        p = &w_ih1[fn * H + fk];
        #pragma unroll
        for (int j = 0; j < 8; ++j) { float v = p[j]; short h = f2bf(v); bihi[j] = h; bilo[j] = f2bf(v - bf2f(h)); }
        p = &w_hh1[fn * H + fk];
        #pragma unroll
        for (int j = 0; j < 8; ++j) { float v = p[j]; short h = f2bf(v); bhhi[j] = h; bhlo[j] = f2bf(v - bf2f(h)); }
    }

    // elementwise-thread mapping: thread t -> (row er, unit eu)
    const int eu = tid & 31;
    const int er = tid >> 5;            // 0..15
    float bias1[4], bias2[4], wx[4];
    #pragma unroll
    for (int g = 0; g < 4; ++g) {
        bias1[g] = b_ih0[g * H + eu] + b_hh0[g * H + eu];
        bias2[g] = b_ih1[g * H + eu] + b_hh1[g * H + eu];
        wx[g]    = w_ih0[g * H + eu];
    }
    float c1 = 0.f, c2 = 0.f, h2last = 0.f;

    // A-frag / C-store addressing
    const int am = lane & 15;           // A row m
    const int ak = fk;                  // A k base
    const int gq = (lane >> 4) * 4;     // C/D row base: row = gq + reg

    __syncthreads();

    for (int s = 0; s < SEQ; ++s) {
        // ---- Phase A: G1 = h1 @ w_hh0^T ; G2-partial = h2 @ w_hh1^T ----
        short8 a1h = *(const short8*)&h1hi[am * H + ak];
        short8 a1l = *(const short8*)&h1lo[am * H + ak];
        short8 a2h = *(const short8*)&h2hi[am * H + ak];
        short8 a2l = *(const short8*)&h2lo[am * H + ak];
        f32x4 g1 = {0.f, 0.f, 0.f, 0.f};
        f32x4 g2 = {0.f, 0.f, 0.f, 0.f};
        g1 = __builtin_amdgcn_mfma_f32_16x16x32_bf16(a1h, b1hi, g1, 0, 0, 0);
        g1 = __builtin_amdgcn_mfma_f32_16x16x32_bf16(a1h, b1lo, g1, 0, 0, 0);
        g1 = __builtin_amdgcn_mfma_f32_16x16x32_bf16(a1l, b1hi, g1, 0, 0, 0);
        g2 = __builtin_amdgcn_mfma_f32_16x16x32_bf16(a2h, bhhi, g2, 0, 0, 0);
        g2 = __builtin_amdgcn_mfma_f32_16x16x32_bf16(a2h, bhlo, g2, 0, 0, 0);
        g2 = __builtin_amdgcn_mfma_f32_16x16x32_bf16(a2l, bhhi, g2, 0, 0, 0);
        #pragma unroll
        for (int j = 0; j < 4; ++j) Gbuf[fn * GSTRIDE + gq + j] = g1[j];
        __syncthreads();

        // ---- Phase B: layer-1 gates + state update ----
        {
            float pi = Gbuf[(0 * H + eu) * GSTRIDE + er];
            float pf = Gbuf[(1 * H + eu) * GSTRIDE + er];
            float pg = Gbuf[(2 * H + eu) * GSTRIDE + er];
            float po = Gbuf[(3 * H + eu) * GSTRIDE + er];
            float xv = xbuf[er * SEQ + s];
            pi += xv * wx[0] + bias1[0];
            pf += xv * wx[1] + bias1[1];
            pg += xv * wx[2] + bias1[2];
            po += xv * wx[3] + bias1[3];
            float iv = fast_sigmoid(pi), fv = fast_sigmoid(pf);
            float gv = fast_tanh(pg),    ov = fast_sigmoid(po);
            c1 = fv * c1 + iv * gv;
            float h1v = ov * fast_tanh(c1);
            short hh = f2bf(h1v);
            h1hi[er * H + eu] = hh;
            h1lo[er * H + eu] = f2bf(h1v - bf2f(hh));
        }
        __syncthreads();

        // ---- Phase C: G2 += h1_new @ w_ih1^T ----
        {
            short8 anh = *(const short8*)&h1hi[am * H + ak];
            short8 anl = *(const short8*)&h1lo[am * H + ak];
            g2 = __builtin_amdgcn_mfma_f32_16x16x32_bf16(anh, bihi, g2, 0, 0, 0);
            g2 = __builtin_amdgcn_mfma_f32_16x16x32_bf16(anh, bilo, g2, 0, 0, 0);
            g2 = __builtin_amdgcn_mfma_f32_16x16x32_bf16(anl, bihi, g2, 0, 0, 0);
            #pragma unroll
            for (int j = 0; j < 4; ++j) Gbuf[fn * GSTRIDE + gq + j] = g2[j];
        }
        __syncthreads();

        // ---- Phase D: layer-2 gates + state update ----
        {
            float pi = Gbuf[(0 * H + eu) * GSTRIDE + er] + bias2[0];
            float pf = Gbuf[(1 * H + eu) * GSTRIDE + er] + bias2[1];
            float pg = Gbuf[(2 * H + eu) * GSTRIDE + er] + bias2[2];
            float po = Gbuf[(3 * H + eu) * GSTRIDE + er] + bias2[3];
            float iv = fast_sigmoid(pi), fv = fast_sigmoid(pf);
            float gv = fast_tanh(pg),    ov = fast_sigmoid(po);
            c2 = fv * c2 + iv * gv;
            float h2v = ov * fast_tanh(c2);
            h2last = h2v;
            short hh = f2bf(h2v);
            h2hi[er * H + eu] = hh;
            h2lo[er * H + eu] = f2bf(h2v - bf2f(hh));
        }
        __syncthreads();
    }

    // ---- FC head: out = leaky(h2 @ fc1^T + b1f, 0.2) @ fc2^T + b2f ----
    h2f[er * 33 + eu] = h2last;
    __syncthreads();
    if (tid < BM * 16) {
        int rr = tid >> 4, j = tid & 15;
        float acc = fc1_b[j];
        #pragma unroll
        for (int k = 0; k < H; ++k) acc += fc1_w[j * H + k] * h2f[rr * 33 + k];
        acc = acc >= 0.f ? acc : 0.2f * acc;
        yb[rr * 17 + j] = acc * fc2_w[j];
    }
    __syncthreads();
    if (tid < BM) {
        float acc = fc2_b[0];
        #pragma unroll
        for (int j = 0; j < 16; ++j) acc += yb[tid * 17 + j];
        out[r0 + tid] = acc;
    }
}

extern "C" void kernel_launch(void* const* d_in, const int* in_sizes, int n_in,
                              void* d_out, int out_size, void* d_ws, size_t ws_size,
                              hipStream_t stream) {
    const float* x     = (const float*)d_in[0];
    const float* w_ih0 = (const float*)d_in[1];
    const float* w_hh0 = (const float*)d_in[2];
    const float* b_ih0 = (const float*)d_in[3];
    const float* b_hh0 = (const float*)d_in[4];
    const float* w_ih1 = (const float*)d_in[5];
    const float* w_hh1 = (const float*)d_in[6];
    const float* b_ih1 = (const float*)d_in[7];
    const float* b_hh1 = (const float*)d_in[8];
    const float* fc1_w = (const float*)d_in[9];
    const float* fc1_b = (const float*)d_in[10];
    const float* fc2_w = (const float*)d_in[11];
    const float* fc2_b = (const float*)d_in[12];
    float* out = (float*)d_out;

    const int B = in_sizes[0] / SEQ;   // 4096
    hipLaunchKernelGGL(lstm_kernel, dim3(B / BM), dim3(NTHREADS), 0, stream,
                       x, w_ih0, w_hh0, b_ih0, b_hh0, w_ih1, w_hh1, b_ih1, b_hh1,
                       fc1_w, fc1_b, fc2_w, fc2_b, out);
}

// Round 3
// 344.112 us; speedup vs baseline: 1.5693x; 1.5693x over previous
//
#include <hip/hip_runtime.h>

#define H 32
#define SEQ 512
#define BM 16          // batch rows per block (= MFMA N)
#define NTHREADS 512   // 8 waves; grid = 4096/16 = 256 -> 1 block/CU
#define HSTRIDE 40     // shorts per h-row: 80B rows -> 16B-aligned b128 frags

typedef __attribute__((ext_vector_type(8))) short short8;
typedef __attribute__((ext_vector_type(4))) float f32x4;

// truncation-split bf16 (error lands in lo; lo trunc error ~2^-15 rel)
__device__ __forceinline__ short hi_bf(float f) { return (short)(__float_as_uint(f) >> 16); }
__device__ __forceinline__ float hi_f(float f)  { return __uint_as_float(__float_as_uint(f) & 0xffff0000u); }

__device__ __forceinline__ float sigm(float x) {
    return __builtin_amdgcn_rcpf(1.0f + __expf(-x));      // v_mul + v_exp + v_add + v_rcp
}
__device__ __forceinline__ float tanh_(float x) {
    return 1.0f - 2.0f * __builtin_amdgcn_rcpf(1.0f + __expf(2.0f * x));
}

__global__ __launch_bounds__(NTHREADS, 2) void lstm_kernel(
    const float* __restrict__ x,      // [4096,512]
    const float* __restrict__ w_ih0,  // [128,1]
    const float* __restrict__ w_hh0,  // [128,32]
    const float* __restrict__ b_ih0, const float* __restrict__ b_hh0,
    const float* __restrict__ w_ih1,  // [128,32]
    const float* __restrict__ w_hh1,  // [128,32]
    const float* __restrict__ b_ih1, const float* __restrict__ b_hh1,
    const float* __restrict__ fc1_w,  // [16,32]
    const float* __restrict__ fc1_b,  // [16]
    const float* __restrict__ fc2_w,  // [1,16]
    const float* __restrict__ fc2_b,  // [1]
    float* __restrict__ out)          // [4096]
{
    __shared__ __align__(16) float xbufT[SEQ * BM];                 // 32 KB, [step][row]
    __shared__ __align__(16) short h1hi[2][BM * HSTRIDE];           // ping-pong h state
    __shared__ __align__(16) short h1lo[2][BM * HSTRIDE];
    __shared__ __align__(16) short h2hi[2][BM * HSTRIDE];
    __shared__ __align__(16) short h2lo[2][BM * HSTRIDE];
    __shared__ __align__(16) float h2f[BM * 33];
    __shared__ __align__(16) float yb[BM * 17];

    const int tid  = threadIdx.x;
    const int lane = tid & 63;
    const int wv   = tid >> 6;          // wave id 0..7
    const int c    = lane & 15;         // frag free-index / batch col
    const int q    = lane >> 4;         // k-quad / D row-group
    const int r0   = blockIdx.x * BM;

    // ---- stage x transposed: xbufT[s][row] (EW read becomes broadcast) ----
    {
        const int row = tid >> 5;           // 0..15
        const int s0  = (tid & 31) * 16;    // 16 steps per thread
        const float* xr = x + (size_t)(r0 + row) * SEQ + s0;
        #pragma unroll
        for (int i = 0; i < 16; i += 4) {
            float4 v = *(const float4*)&xr[i];
            xbufT[(s0 + i + 0) * BM + row] = v.x;
            xbufT[(s0 + i + 1) * BM + row] = v.y;
            xbufT[(s0 + i + 2) * BM + row] = v.z;
            xbufT[(s0 + i + 3) * BM + row] = v.w;
        }
    }
    // zero both h ping-pong buffers
    {
        int* z = (int*)&h1hi[0][0];   // the four arrays are contiguous? not guaranteed -> zero each
        (void)z;
        for (int i = tid; i < BM * HSTRIDE; i += NTHREADS) {
            h1hi[0][i] = 0; h1hi[1][i] = 0; h1lo[0][i] = 0; h1lo[1][i] = 0;
            h2hi[0][i] = 0; h2hi[1][i] = 0; h2lo[0][i] = 0; h2lo[1][i] = 0;
        }
    }

    // ---- static W fragments (A-operand), tile rows permuted: r -> (gate r&3, unit 4wv+(r>>2)) ----
    const int worig = (c & 3) * H + 4 * wv + (c >> 2);   // original W row for frag row c
    const int kb    = 8 * q;
    short8 w0h, w0l, wih, wil, whh, whl;
    {
        const float* p = &w_hh0[worig * H + kb];
        #pragma unroll
        for (int j = 0; j < 8; ++j) { float v = p[j]; w0h[j] = hi_bf(v); w0l[j] = hi_bf(v - hi_f(v)); }
        p = &w_ih1[worig * H + kb];
        #pragma unroll
        for (int j = 0; j < 8; ++j) { float v = p[j]; wih[j] = hi_bf(v); wil[j] = hi_bf(v - hi_f(v)); }
        p = &w_hh1[worig * H + kb];
        #pragma unroll
        for (int j = 0; j < 8; ++j) { float v = p[j]; whh[j] = hi_bf(v); whl[j] = hi_bf(v - hi_f(v)); }
    }

    // ---- per-lane cell: batch m = c, unit u = 4*wv + q; biases folded into acc init ----
    const int m = c;
    const int u = 4 * wv + q;
    f32x4 bias1v, bias2v;
    float wx[4];
    #pragma unroll
    for (int g = 0; g < 4; ++g) {
        bias1v[g] = b_ih0[g * H + u] + b_hh0[g * H + u];
        bias2v[g] = b_ih1[g * H + u] + b_hh1[g * H + u];
        wx[g]     = w_ih0[g * H + u];
    }
    float c1 = 0.f, c2 = 0.f, h2last = 0.f;

    const int fofs = c * HSTRIDE + kb;   // b128 frag read offset (shorts)
    const int hofs = m * HSTRIDE + u;    // h write offset (shorts)

    __syncthreads();

    // pipelined: iter t computes layer-1 step t and layer-2 step t-1. 1 barrier/iter.
    for (int t = 0; t <= SEQ; ++t) {
        const int cur = t & 1, nxt = cur ^ 1;

        // B-operand fragments (h state), 4x ds_read_b128
        short8 a1h = *(const short8*)&h1hi[cur][fofs];
        short8 a1l = *(const short8*)&h1lo[cur][fofs];
        short8 a2h = *(const short8*)&h2hi[cur][fofs];
        short8 a2l = *(const short8*)&h2lo[cur][fofs];

        // G1 = Whh0 . h1(t-1)^T + bias1 ; G2 = Wih1 . h1(t-1)^T + Whh1 . h2(t-2)^T + bias2
        f32x4 g1 = bias1v, g2 = bias2v;
        g1 = __builtin_amdgcn_mfma_f32_16x16x32_bf16(w0h, a1h, g1, 0, 0, 0);
        g1 = __builtin_amdgcn_mfma_f32_16x16x32_bf16(w0h, a1l, g1, 0, 0, 0);
        g1 = __builtin_amdgcn_mfma_f32_16x16x32_bf16(w0l, a1h, g1, 0, 0, 0);
        g2 = __builtin_amdgcn_mfma_f32_16x16x32_bf16(wih, a1h, g2, 0, 0, 0);
        g2 = __builtin_amdgcn_mfma_f32_16x16x32_bf16(wih, a1l, g2, 0, 0, 0);
        g2 = __builtin_amdgcn_mfma_f32_16x16x32_bf16(wil, a1h, g2, 0, 0, 0);
        g2 = __builtin_amdgcn_mfma_f32_16x16x32_bf16(whh, a2h, g2, 0, 0, 0);
        g2 = __builtin_amdgcn_mfma_f32_16x16x32_bf16(whh, a2l, g2, 0, 0, 0);
        g2 = __builtin_amdgcn_mfma_f32_16x16x32_bf16(whl, a2h, g2, 0, 0, 0);

        // ---- layer-1 elementwise, step t (in-register: g1 = i,f,g,o of cell (m,u)) ----
        if (t < SEQ) {
            float xv = xbufT[t * BM + m];
            float pi = g1[0] + xv * wx[0];
            float pf = g1[1] + xv * wx[1];
            float pg = g1[2] + xv * wx[2];
            float po = g1[3] + xv * wx[3];
            float iv = sigm(pi), fv = sigm(pf), gv = tanh_(pg), ov = sigm(po);
            c1 = fv * c1 + iv * gv;
            float h1v = ov * tanh_(c1);
            float hh  = hi_f(h1v);
            h1hi[nxt][hofs] = hi_bf(h1v);
            h1lo[nxt][hofs] = hi_bf(h1v - hh);
        }
        // ---- layer-2 elementwise, step t-1 ----
        if (t > 0) {
            float iv = sigm(g2[0]), fv = sigm(g2[1]), gv = tanh_(g2[2]), ov = sigm(g2[3]);
            c2 = fv * c2 + iv * gv;
            float h2v = ov * tanh_(c2);
            h2last = h2v;
            float hh = hi_f(h2v);
            h2hi[nxt][hofs] = hi_bf(h2v);
            h2lo[nxt][hofs] = hi_bf(h2v - hh);
        }
        __syncthreads();
    }

    // ---- FC head ----
    h2f[m * 33 + u] = h2last;            // every lane owns one (m,u) cell
    __syncthreads();
    if (tid < BM * 16) {
        int rr = tid >> 4, j = tid & 15;
        float acc = fc1_b[j];
        #pragma unroll
        for (int k = 0; k < H; ++k) acc += fc1_w[j * H + k] * h2f[rr * 33 + k];
        acc = acc >= 0.f ? acc : 0.2f * acc;
        yb[rr * 17 + j] = acc * fc2_w[j];
    }
    __syncthreads();
    if (tid < BM) {
        float acc = fc2_b[0];
        #pragma unroll
        for (int j = 0; j < 16; ++j) acc += yb[tid * 17 + j];
        out[r0 + tid] = acc;
    }
}

extern "C" void kernel_launch(void* const* d_in, const int* in_sizes, int n_in,
                              void* d_out, int out_size, void* d_ws, size_t ws_size,
                              hipStream_t stream) {
    const float* x     = (const float*)d_in[0];
    const float* w_ih0 = (const float*)d_in[1];
    const float* w_hh0 = (const float*)d_in[2];
    const float* b_ih0 = (const float*)d_in[3];
    const float* b_hh0 = (const float*)d_in[4];
    const float* w_ih1 = (const float*)d_in[5];
    const float* w_hh1 = (const float*)d_in[6];
    const float* b_ih1 = (const float*)d_in[7];
    const float* b_hh1 = (const float*)d_in[8];
    const float* fc1_w = (const float*)d_in[9];
    const float* fc1_b = (const float*)d_in[10];
    const float* fc2_w = (const float*)d_in[11];
    const float* fc2_b = (const float*)d_in[12];
    float* out = (float*)d_out;

    const int B = in_sizes[0] / SEQ;   // 4096
    hipLaunchKernelGGL(lstm_kernel, dim3(B / BM), dim3(NTHREADS), 0, stream,
                       x, w_ih0, w_hh0, b_ih0, b_hh0, w_ih1, w_hh1, b_ih1, b_hh1,
                       fc1_w, fc1_b, fc2_w, fc2_b, out);
}

// Round 4
// 343.153 us; speedup vs baseline: 1.5737x; 1.0028x over previous
//
#include <hip/hip_runtime.h>

#define H 32
#define SEQ 512
#define BM 16          // batch rows per block (= MFMA N)
#define NTHREADS 512   // 8 waves; grid = 4096/16 = 256 -> 1 block/CU
#define HSTRIDE 40     // halves per h-row: 80B rows -> 16B-aligned b128 frags, 2-way banks on reads

typedef _Float16 half8 __attribute__((ext_vector_type(8)));
typedef __attribute__((ext_vector_type(4))) float f32x4;

#define L2E 1.44269504088896340736f

__device__ __forceinline__ float rcp_(float x) { return __builtin_amdgcn_rcpf(x); }

__global__ __launch_bounds__(NTHREADS, 2) void lstm_kernel(
    const float* __restrict__ x,      // [4096,512]
    const float* __restrict__ w_ih0,  // [128,1]
    const float* __restrict__ w_hh0,  // [128,32]
    const float* __restrict__ b_ih0, const float* __restrict__ b_hh0,
    const float* __restrict__ w_ih1,  // [128,32]
    const float* __restrict__ w_hh1,  // [128,32]
    const float* __restrict__ b_ih1, const float* __restrict__ b_hh1,
    const float* __restrict__ fc1_w,  // [16,32]
    const float* __restrict__ fc1_b,  // [16]
    const float* __restrict__ fc2_w,  // [1,16]
    const float* __restrict__ fc2_b,  // [1]
    float* __restrict__ out)          // [4096]
{
    __shared__ __align__(16) float    xbufT[SEQ * BM];            // 32 KB, [step][row]
    __shared__ __align__(16) _Float16 h1s[2][BM * HSTRIDE];       // ping-pong h1 (fp16)
    __shared__ __align__(16) _Float16 h2s[2][BM * HSTRIDE];       // ping-pong h2 (fp16)
    __shared__ __align__(16) float    h2f[BM * 33];
    __shared__ __align__(16) float    yb[BM * 17];

    const int tid  = threadIdx.x;
    const int lane = tid & 63;
    const int wv   = tid >> 6;          // wave id 0..7
    const int c    = lane & 15;         // frag free-index / batch col
    const int q    = lane >> 4;         // k-quad / D row-group
    const int r0   = blockIdx.x * BM;

    // ---- stage x transposed: xbufT[s][row] ----
    {
        const int row = tid >> 5;           // 0..15
        const int s0  = (tid & 31) * 16;    // 16 steps per thread
        const float* xr = x + (size_t)(r0 + row) * SEQ + s0;
        #pragma unroll
        for (int i = 0; i < 16; i += 4) {
            float4 v = *(const float4*)&xr[i];
            xbufT[(s0 + i + 0) * BM + row] = v.x;
            xbufT[(s0 + i + 1) * BM + row] = v.y;
            xbufT[(s0 + i + 2) * BM + row] = v.z;
            xbufT[(s0 + i + 3) * BM + row] = v.w;
        }
    }
    for (int i = tid; i < BM * HSTRIDE; i += NTHREADS) {
        h1s[0][i] = (_Float16)0.f; h1s[1][i] = (_Float16)0.f;
        h2s[0][i] = (_Float16)0.f; h2s[1][i] = (_Float16)0.f;
    }

    // ---- static W fragments (A-operand), rows permuted r -> (gate r&3, unit 4wv + r>>2) ----
    // gate scales folded in (i,f,o: -log2e ; g: +2*log2e) so EW uses raw exp2f.
    const float gsc[4] = { -L2E, -L2E, 2.f * L2E, -L2E };
    const int worig = (c & 3) * H + 4 * wv + (c >> 2);
    const float wsc = gsc[c & 3];
    const int kb = 8 * q;
    half8 w0h, w0l, wih, wil, whh, whl;
    {
        const float* p = &w_hh0[worig * H + kb];
        #pragma unroll
        for (int j = 0; j < 8; ++j) { float v = p[j] * wsc; _Float16 h = (_Float16)v; w0h[j] = h; w0l[j] = (_Float16)(v - (float)h); }
        p = &w_ih1[worig * H + kb];
        #pragma unroll
        for (int j = 0; j < 8; ++j) { float v = p[j] * wsc; _Float16 h = (_Float16)v; wih[j] = h; wil[j] = (_Float16)(v - (float)h); }
        p = &w_hh1[worig * H + kb];
        #pragma unroll
        for (int j = 0; j < 8; ++j) { float v = p[j] * wsc; _Float16 h = (_Float16)v; whh[j] = h; whl[j] = (_Float16)(v - (float)h); }
    }

    // per-lane cell: batch m = c, unit u = 4*wv + q
    const int m = c;
    const int u = 4 * wv + q;
    f32x4 bias1v, bias2v;
    float wx[4];
    #pragma unroll
    for (int g = 0; g < 4; ++g) {
        bias1v[g] = (b_ih0[g * H + u] + b_hh0[g * H + u]) * gsc[g];
        bias2v[g] = (b_ih1[g * H + u] + b_hh1[g * H + u]) * gsc[g];
        wx[g]     = w_ih0[g * H + u] * gsc[g];
    }
    float c1 = 0.f, c2 = 0.f, h2last = 0.f;

    const int fofs = c * HSTRIDE + kb;   // b128 frag read offset (halves)
    const int hofs = m * HSTRIDE + u;    // h write offset (halves)

    __syncthreads();

    // shared-rcp LSTM cell: 5 exp2 + 2 rcp
    auto cell = [&](const f32x4& g, float& cst) -> float {
        float ei = exp2f(g[0]);
        float ef = exp2f(g[1]);
        float eg = exp2f(g[2]);
        float eo = exp2f(g[3]);
        float A  = 1.f + ei;           // 1/i
        float F  = 1.f + ef;           // 1/f
        float Gp = eg + 1.f, Gm = eg - 1.f;
        float t1 = A * Gp;
        float num = fmaf(cst, t1, Gm * F);
        float cn  = num * rcp_(F * t1);
        cn = fminf(fmaxf(cn, -12.f), 12.f);
        cst = cn;
        float ec = exp2f(cn * (2.f * L2E));
        return (ec - 1.f) * rcp_((1.f + eo) * (ec + 1.f));
    };

    // one pipelined step: iter t computes layer-1 step t, layer-2 step t-1
    auto do_step = [&](const _Float16* __restrict__ h1r, const _Float16* __restrict__ h2r,
                       _Float16* __restrict__ h1w, _Float16* __restrict__ h2w,
                       int t, bool ew1, bool ew2) {
        half8 a1 = *(const half8*)(h1r + fofs);
        half8 a2 = *(const half8*)(h2r + fofs);
        float xv = 0.f;
        if (ew1) xv = xbufT[t * BM + m];
        f32x4 g1 = bias1v, g2 = bias2v;
        g1 = __builtin_amdgcn_mfma_f32_16x16x32_f16(w0h, a1, g1, 0, 0, 0);
        g1 = __builtin_amdgcn_mfma_f32_16x16x32_f16(w0l, a1, g1, 0, 0, 0);
        g2 = __builtin_amdgcn_mfma_f32_16x16x32_f16(wih, a1, g2, 0, 0, 0);
        g2 = __builtin_amdgcn_mfma_f32_16x16x32_f16(wil, a1, g2, 0, 0, 0);
        g2 = __builtin_amdgcn_mfma_f32_16x16x32_f16(whh, a2, g2, 0, 0, 0);
        g2 = __builtin_amdgcn_mfma_f32_16x16x32_f16(whl, a2, g2, 0, 0, 0);
        if (ew1) {
            #pragma unroll
            for (int j = 0; j < 4; ++j) g1[j] = fmaf(xv, wx[j], g1[j]);
            float h1v = cell(g1, c1);
            h1w[hofs] = (_Float16)h1v;
        }
        if (ew2) {
            float h2v = cell(g2, c2);
            h2last = h2v;
            h2w[hofs] = (_Float16)h2v;
        }
        __syncthreads();
    };

    do_step(h1s[0], h2s[0], h1s[1], h2s[1], 0, true, false);
    for (int tt = 0; tt < 255; ++tt) {
        int t = 1 + 2 * tt;
        do_step(h1s[1], h2s[1], h1s[0], h2s[0], t,     true, true);
        do_step(h1s[0], h2s[0], h1s[1], h2s[1], t + 1, true, true);
    }
    do_step(h1s[1], h2s[1], h1s[0], h2s[0], 511, true, true);
    do_step(h1s[0], h2s[0], h1s[1], h2s[1], 512, false, true);

    // ---- FC head ----
    h2f[m * 33 + u] = h2last;
    __syncthreads();
    if (tid < BM * 16) {
        int rr = tid >> 4, j = tid & 15;
        float acc = fc1_b[j];
        #pragma unroll
        for (int k = 0; k < H; ++k) acc += fc1_w[j * H + k] * h2f[rr * 33 + k];
        acc = acc >= 0.f ? acc : 0.2f * acc;
        yb[rr * 17 + j] = acc * fc2_w[j];
    }
    __syncthreads();
    if (tid < BM) {
        float acc = fc2_b[0];
        #pragma unroll
        for (int j = 0; j < 16; ++j) acc += yb[tid * 17 + j];
        out[r0 + tid] = acc;
    }
}

extern "C" void kernel_launch(void* const* d_in, const int* in_sizes, int n_in,
                              void* d_out, int out_size, void* d_ws, size_t ws_size,
                              hipStream_t stream) {
    const float* x     = (const float*)d_in[0];
    const float* w_ih0 = (const float*)d_in[1];
    const float* w_hh0 = (const float*)d_in[2];
    const float* b_ih0 = (const float*)d_in[3];
    const float* b_hh0 = (const float*)d_in[4];
    const float* w_ih1 = (const float*)d_in[5];
    const float* w_hh1 = (const float*)d_in[6];
    const float* b_ih1 = (const float*)d_in[7];
    const float* b_hh1 = (const float*)d_in[8];
    const float* fc1_w = (const float*)d_in[9];
    const float* fc1_b = (const float*)d_in[10];
    const float* fc2_w = (const float*)d_in[11];
    const float* fc2_b = (const float*)d_in[12];
    float* out = (float*)d_out;

    const int B = in_sizes[0] / SEQ;   // 4096
    hipLaunchKernelGGL(lstm_kernel, dim3(B / BM), dim3(NTHREADS), 0, stream,
                       x, w_ih0, w_hh0, b_ih0, b_hh0, w_ih1, w_hh1, b_ih1, b_hh1,
                       fc1_w, fc1_b, fc2_w, fc2_b, out);
}

// Round 5
// 272.649 us; speedup vs baseline: 1.9806x; 1.2586x over previous
//
#include <hip/hip_runtime.h>

#define H 32
#define SEQ 512
#define BM 16          // batch rows per block (= MFMA N)
#define NTHREADS 512   // 8 waves; grid = 4096/16 = 256 -> 1 block/CU
#define HSTRIDE 40     // halves per h-row: 80B rows -> 16B-aligned b128 frags

typedef _Float16 half8 __attribute__((ext_vector_type(8)));
typedef __attribute__((ext_vector_type(4))) float f32x4;

#define L2E 1.44269504088896340736f

__device__ __forceinline__ float rcp_(float x)  { return __builtin_amdgcn_rcpf(x); }
__device__ __forceinline__ float exp2_(float x) { return __builtin_amdgcn_exp2f(x); }  // raw v_exp_f32

__global__ __launch_bounds__(NTHREADS, 2) void lstm_kernel(
    const float* __restrict__ x,      // [4096,512]
    const float* __restrict__ w_ih0,  // [128,1]
    const float* __restrict__ w_hh0,  // [128,32]
    const float* __restrict__ b_ih0, const float* __restrict__ b_hh0,
    const float* __restrict__ w_ih1,  // [128,32]
    const float* __restrict__ w_hh1,  // [128,32]
    const float* __restrict__ b_ih1, const float* __restrict__ b_hh1,
    const float* __restrict__ fc1_w,  // [16,32]
    const float* __restrict__ fc1_b,  // [16]
    const float* __restrict__ fc2_w,  // [1,16]
    const float* __restrict__ fc2_b,  // [1]
    float* __restrict__ out)          // [4096]
{
    __shared__ __align__(16) float    xbufT[SEQ * BM];            // 32 KB, [step][row]
    __shared__ __align__(16) _Float16 h1s[2][BM * HSTRIDE];       // ping-pong h1 (fp16)
    __shared__ __align__(16) _Float16 h2s[2][BM * HSTRIDE];       // ping-pong h2 (fp16)
    __shared__ __align__(16) float    h2f[BM * 33];
    __shared__ __align__(16) float    yb[BM * 17];

    const int tid  = threadIdx.x;
    const int lane = tid & 63;
    const int wv   = tid >> 6;          // wave id 0..7
    const int c    = lane & 15;         // frag free-index / batch col
    const int q    = lane >> 4;         // k-quad / D row-group
    const int r0   = blockIdx.x * BM;

    // ---- stage x transposed: xbufT[s][row] ----
    {
        const int row = tid >> 5;           // 0..15
        const int s0  = (tid & 31) * 16;    // 16 steps per thread
        const float* xr = x + (size_t)(r0 + row) * SEQ + s0;
        #pragma unroll
        for (int i = 0; i < 16; i += 4) {
            float4 v = *(const float4*)&xr[i];
            xbufT[(s0 + i + 0) * BM + row] = v.x;
            xbufT[(s0 + i + 1) * BM + row] = v.y;
            xbufT[(s0 + i + 2) * BM + row] = v.z;
            xbufT[(s0 + i + 3) * BM + row] = v.w;
        }
    }
    for (int i = tid; i < BM * HSTRIDE; i += NTHREADS) {
        h1s[0][i] = (_Float16)0.f; h1s[1][i] = (_Float16)0.f;
        h2s[0][i] = (_Float16)0.f; h2s[1][i] = (_Float16)0.f;
    }

    // ---- static W fragments (A-operand), rows permuted r -> (gate r&3, unit 4wv + r>>2) ----
    // gate scales folded in (i,f,o: -log2e ; g: +2*log2e) so EW uses raw v_exp_f32.
    const float gsc[4] = { -L2E, -L2E, 2.f * L2E, -L2E };
    const int worig = (c & 3) * H + 4 * wv + (c >> 2);
    const float wsc = gsc[c & 3];
    const int kb = 8 * q;
    half8 w0h, w0l, wih, wil, whh, whl;
    {
        const float* p = &w_hh0[worig * H + kb];
        #pragma unroll
        for (int j = 0; j < 8; ++j) { float v = p[j] * wsc; _Float16 h = (_Float16)v; w0h[j] = h; w0l[j] = (_Float16)(v - (float)h); }
        p = &w_ih1[worig * H + kb];
        #pragma unroll
        for (int j = 0; j < 8; ++j) { float v = p[j] * wsc; _Float16 h = (_Float16)v; wih[j] = h; wil[j] = (_Float16)(v - (float)h); }
        p = &w_hh1[worig * H + kb];
        #pragma unroll
        for (int j = 0; j < 8; ++j) { float v = p[j] * wsc; _Float16 h = (_Float16)v; whh[j] = h; whl[j] = (_Float16)(v - (float)h); }
    }

    // per-lane cell: batch m = c, unit u = 4*wv + q
    const int m = c;
    const int u = 4 * wv + q;
    f32x4 bias1v, bias2v;
    float wx[4];
    #pragma unroll
    for (int g = 0; g < 4; ++g) {
        bias1v[g] = (b_ih0[g * H + u] + b_hh0[g * H + u]) * gsc[g];
        bias2v[g] = (b_ih1[g * H + u] + b_hh1[g * H + u]) * gsc[g];
        wx[g]     = w_ih0[g * H + u] * gsc[g];
    }
    float c1 = 0.f, c2 = 0.f, h2last = 0.f;

    const int fofs = c * HSTRIDE + kb;   // b128 frag read offset (halves)
    const int hofs = m * HSTRIDE + u;    // h write offset (halves)

    __syncthreads();

    // shared-rcp LSTM cell: 5 v_exp + 2 v_rcp
    auto cell = [&](const f32x4& g, float& cst) -> float {
        float ei = exp2_(g[0]);
        float ef = exp2_(g[1]);
        float eg = exp2_(g[2]);
        float eo = exp2_(g[3]);
        float A  = 1.f + ei;           // 1/i
        float F  = 1.f + ef;           // 1/f
        float Gp = eg + 1.f, Gm = eg - 1.f;
        float t1 = A * Gp;
        float num = fmaf(cst, t1, Gm * F);
        float cn  = num * rcp_(F * t1);
        cn = fminf(fmaxf(cn, -12.f), 12.f);
        cst = cn;
        float ec = exp2_(cn * (2.f * L2E));
        return (ec - 1.f) * rcp_((1.f + eo) * (ec + 1.f));
    };

    // one pipelined step: iter t computes layer-1 step t, layer-2 step t-1
    auto do_step = [&](const _Float16* __restrict__ h1r, const _Float16* __restrict__ h2r,
                       _Float16* __restrict__ h1w, _Float16* __restrict__ h2w,
                       int t, bool ew1, bool ew2) {
        half8 a1 = *(const half8*)(h1r + fofs);
        half8 a2 = *(const half8*)(h2r + fofs);
        float xv = 0.f;
        if (ew1) xv = xbufT[t * BM + m];
        f32x4 g1 = bias1v, g2a = bias2v;
        f32x4 g2b = {0.f, 0.f, 0.f, 0.f};
        // two independent 2-deep chains per gate-set (halve serial MFMA latency)
        g1  = __builtin_amdgcn_mfma_f32_16x16x32_f16(w0h, a1, g1,  0, 0, 0);
        g2a = __builtin_amdgcn_mfma_f32_16x16x32_f16(wih, a1, g2a, 0, 0, 0);
        g2b = __builtin_amdgcn_mfma_f32_16x16x32_f16(whh, a2, g2b, 0, 0, 0);
        g1  = __builtin_amdgcn_mfma_f32_16x16x32_f16(w0l, a1, g1,  0, 0, 0);
        g2a = __builtin_amdgcn_mfma_f32_16x16x32_f16(wil, a1, g2a, 0, 0, 0);
        g2b = __builtin_amdgcn_mfma_f32_16x16x32_f16(whl, a2, g2b, 0, 0, 0);
        if (ew1) {
            #pragma unroll
            for (int j = 0; j < 4; ++j) g1[j] = fmaf(xv, wx[j], g1[j]);
            float h1v = cell(g1, c1);
            h1w[hofs] = (_Float16)h1v;
        }
        if (ew2) {
            f32x4 g2;
            #pragma unroll
            for (int j = 0; j < 4; ++j) g2[j] = g2a[j] + g2b[j];
            float h2v = cell(g2, c2);
            h2last = h2v;
            h2w[hofs] = (_Float16)h2v;
        }
        __syncthreads();
    };

    do_step(h1s[0], h2s[0], h1s[1], h2s[1], 0, true, false);
    for (int tt = 0; tt < 255; ++tt) {
        int t = 1 + 2 * tt;
        do_step(h1s[1], h2s[1], h1s[0], h2s[0], t,     true, true);
        do_step(h1s[0], h2s[0], h1s[1], h2s[1], t + 1, true, true);
    }
    do_step(h1s[1], h2s[1], h1s[0], h2s[0], 511, true, true);
    do_step(h1s[0], h2s[0], h1s[1], h2s[1], 512, false, true);

    // ---- FC head ----
    h2f[m * 33 + u] = h2last;
    __syncthreads();
    if (tid < BM * 16) {
        int rr = tid >> 4, j = tid & 15;
        float acc = fc1_b[j];
        #pragma unroll
        for (int k = 0; k < H; ++k) acc += fc1_w[j * H + k] * h2f[rr * 33 + k];
        acc = acc >= 0.f ? acc : 0.2f * acc;
        yb[rr * 17 + j] = acc * fc2_w[j];
    }
    __syncthreads();
    if (tid < BM) {
        float acc = fc2_b[0];
        #pragma unroll
        for (int j = 0; j < 16; ++j) acc += yb[tid * 17 + j];
        out[r0 + tid] = acc;
    }
}

extern "C" void kernel_launch(void* const* d_in, const int* in_sizes, int n_in,
                              void* d_out, int out_size, void* d_ws, size_t ws_size,
                              hipStream_t stream) {
    const float* x     = (const float*)d_in[0];
    const float* w_ih0 = (const float*)d_in[1];
    const float* w_hh0 = (const float*)d_in[2];
    const float* b_ih0 = (const float*)d_in[3];
    const float* b_hh0 = (const float*)d_in[4];
    const float* w_ih1 = (const float*)d_in[5];
    const float* w_hh1 = (const float*)d_in[6];
    const float* b_ih1 = (const float*)d_in[7];
    const float* b_hh1 = (const float*)d_in[8];
    const float* fc1_w = (const float*)d_in[9];
    const float* fc1_b = (const float*)d_in[10];
    const float* fc2_w = (const float*)d_in[11];
    const float* fc2_b = (const float*)d_in[12];
    float* out = (float*)d_out;

    const int B = in_sizes[0] / SEQ;   // 4096
    hipLaunchKernelGGL(lstm_kernel, dim3(B / BM), dim3(NTHREADS), 0, stream,
                       x, w_ih0, w_hh0, b_ih0, b_hh0, w_ih1, w_hh1, b_ih1, b_hh1,
                       fc1_w, fc1_b, fc2_w, fc2_b, out);
}